// Round 16
// baseline (635.592 us; speedup 1.0000x reference)
//
#include <hip/hip_runtime.h>
#include <math.h>

#define B_ 4
#define CIN_ 32
#define HID_ 32
#define T_ 31
#define H_ 96
#define W_ 96
#define SP_ (H_*W_)
#define TSP (T_ * SP_)

typedef _Float16 half8 __attribute__((ext_vector_type(8)));
typedef float f32x4 __attribute__((ext_vector_type(4)));
typedef float f32x16 __attribute__((ext_vector_type(16)));

static __device__ inline unsigned int packhh(float a, float b) {
  unsigned short ua = __builtin_bit_cast(unsigned short, (_Float16)a);
  unsigned short ub = __builtin_bit_cast(unsigned short, (_Float16)b);
  return (unsigned int)ua | ((unsigned int)ub << 16);
}

// ---------------------------------------------------------------------------
// Kernel 0: weights fp32 -> fp16 gate-interleaved MFMA A-fragments.
// wr[((ocg*27 + tap)*64 + lane)*8 + i]
//   m = lane&15: gate = m&1, ch = ocg*8 + (m>>1); oc = gate*32 + ch
//   cin = (lane>>4)*8 + i
// ---------------------------------------------------------------------------
__global__ __launch_bounds__(256) void prep_w_kernel(
    const float* __restrict__ w, _Float16* __restrict__ wr) {
  int idx = blockIdx.x * 256 + threadIdx.x;
  if (idx >= 55296) return;
  int i = idx & 7;
  int lane = (idx >> 3) & 63;
  int rest = idx >> 9;             // ocg*27 + tap
  int tap = rest % 27;
  int ocg = rest / 27;
  int m = lane & 15;
  int cin = (lane >> 4) * 8 + i;
  int oc = (m & 1) * 32 + ocg * 8 + (m >> 1);
  wr[idx] = (_Float16)(w[(oc * CIN_ + cin) * 27 + tap]);
}

// ---------------------------------------------------------------------------
// Kernel 1: fused Conv3d (fp16 MFMA) + gating + SERIAL recurrence.
// R10/R11 proven schedule; partition changed for GRID BALANCE:
// block = 2 waves (128 thr) owning ONE channel-half (32 oc: ocg = half*2+wv);
// two blocks per 16x6 tile -> grid (192,4) = 768 blocks = EXACTLY 3/CU
// (R10/R11's 384 = 1.5/CU makespan imbalance was the measured limiter:
// Occupancy 15%, half the CUs idle half the time).
// LDS: 4-slot ring x 11520 B = 46 KB -> 3 blocks/CU = 138 KB. Twin blocks
// duplicate staging reads (L3-absorbed; input fits 256MB L3).
// Per wave: R10's exact budget - 108 weight VGPR, acc[6], 162 MFMA/t,
// 72 ds_read_b128/t; stores after barrier; NO swizzle.
// launch_bounds(128,2) caps at 256 VGPR (no spill; R12 proved ~228 ok).
// ---------------------------------------------------------------------------
#define PITCH 40
#define SROWS 8
#define SCOLS 18
#define RST (SCOLS * PITCH)
#define SLICE_HF (SROWS * RST)             // 5760 f16 = 11520 B

__global__ __launch_bounds__(128, 2) void conv_rec_mfma(
    const float* __restrict__ in, const _Float16* __restrict__ wr,
    const float* __restrict__ bias, unsigned int* __restrict__ gout) {
  __shared__ _Float16 in_s[4 * SLICE_HF];   // 46080 B

  const int tid = threadIdx.x;
  const int bx = blockIdx.x;     // 0..191
  const int tile = bx >> 1;      // 0..95
  const int half = bx & 1;       // channel-half
  const int b = blockIdx.y;      // 0..3
  const int x0 = (tile % 6) * 16;
  const int y0 = (tile / 6) * 6;
  const int lane = tid & 63;
  const int wv = tid >> 6;       // 0..1
  const int ocg = half * 2 + wv; // 0..3 (same meaning as R10)
  const int px = lane & 15;
  const int kq = lane >> 4;      // 0..3

  // per-wave weights: 27 taps, gate-interleaved 16-slot frags (108 VGPR)
  half8 wreg[27];
  {
    const _Float16* wp = wr + (size_t)ocg * 27 * 512 + lane * 8;
#pragma unroll
    for (int tap = 0; tap < 27; ++tap)
      wreg[tap] = *(const half8*)(wp + tap * 512);
  }

  const int c0 = ocg * 8 + 2 * kq;
  f32x4 bias4;
  bias4[0] = bias[c0];
  bias4[1] = bias[32 + c0];
  bias4[2] = bias[c0 + 1];
  bias4[3] = bias[32 + c0 + 1];

  // staging roles (128 thr): interior 32 jobs (rj = k*8 + s_q -> 8r x 32cin);
  // edges: e_cin = tid&31, rows e_y4 and e_y4+4.
  const int s_xi = tid & 15;
  const int s_q  = tid >> 4;       // 0..7
  const int e_cin = tid & 31;
  const int e_y4  = tid >> 5;      // 0..3
  const bool has_l = (x0 > 0), has_r = (x0 + 16 < W_);

  const float* inb = in + (size_t)(b * CIN_) * TSP;

  auto stage_full = [&](int ts) {   // prologue only
    _Float16* dst = in_s + (ts & 3) * SLICE_HF;
    const int tso = ts * SP_;
#pragma unroll
    for (int k = 0; k < 32; ++k) {
      int rj = k * 8 + s_q;
      int cin = rj & 31;
      int yy = rj >> 5;
      int gy = y0 - 1 + yy;
      float v = 0.f;
      if ((unsigned)gy < (unsigned)H_)
        v = inb[(size_t)cin * TSP + tso + gy * W_ + x0 + s_xi];
      dst[(yy * SCOLS + s_xi + 1) * PITCH + cin] = (_Float16)v;
    }
#pragma unroll
    for (int j = 0; j < 2; ++j) {
      int yy = e_y4 + 4 * j;
      int gy = y0 - 1 + yy;
      float vl = 0.f, vr = 0.f;
      if ((unsigned)gy < (unsigned)H_) {
        const float* rb = inb + (size_t)e_cin * TSP + tso + gy * W_;
        if (has_l) vl = rb[x0 - 1];
        if (has_r) vr = rb[x0 + 16];
      }
      dst[(yy * SCOLS + 0) * PITCH + e_cin] = (_Float16)vl;
      dst[(yy * SCOLS + 17) * PITCH + e_cin] = (_Float16)vr;
    }
  };

  // prologue: slot 3 = slice -1 = zeros; slices 0,1 staged
  {
    uint32_t* dz = (uint32_t*)(in_s + 3 * SLICE_HF);
    for (int e = tid; e < SLICE_HF / 2; e += 128) dz[e] = 0u;
  }
  stage_full(0);
  stage_full(1);
  __syncthreads();

  float h[6][2];
#pragma unroll
  for (int r = 0; r < 6; ++r) { h[r][0] = 0.f; h[r][1] = 0.f; }

  const int pr = ocg * 4 + kq;   // packed pair plane 0..15
  size_t obase = ((size_t)(b * 32 + pr) * T_) * SP_ + y0 * W_ + x0 + px;

  // brow column offsets (no swizzle)
  int cs[3];
#pragma unroll
  for (int kw = 0; kw < 3; ++kw) cs[kw] = (px + kw) * PITCH + kq * 8;

  for (int t = 0; t < T_; ++t) {
    const int ts = t + 2;

    // ---- phase A: issue stage loads for slice ts (held in regs) ----
    float sv[32], el[2] = {0.f, 0.f}, er[2] = {0.f, 0.f};
    if (ts < T_) {
      const int tso = ts * SP_;
#pragma unroll
      for (int k = 0; k < 32; ++k) {
        int rj = k * 8 + s_q;
        int cin = rj & 31;
        int yy = rj >> 5;
        int gy = y0 - 1 + yy;
        sv[k] = 0.f;
        if ((unsigned)gy < (unsigned)H_)
          sv[k] = inb[(size_t)cin * TSP + tso + gy * W_ + x0 + s_xi];
      }
#pragma unroll
      for (int j = 0; j < 2; ++j) {
        int gy = y0 - 1 + e_y4 + 4 * j;
        if ((unsigned)gy < (unsigned)H_) {
          const float* rb = inb + (size_t)e_cin * TSP + tso + gy * W_;
          if (has_l) el[j] = rb[x0 - 1];
          if (has_r) er[j] = rb[x0 + 16];
        }
      }
    }

    // ---- compute: 27 taps x 6 rows (R10 body, unchanged) ----
    f32x4 acc[6];
#pragma unroll
    for (int r = 0; r < 6; ++r) acc[r] = bias4;

#pragma unroll
    for (int kd = 0; kd < 3; ++kd) {
      const _Float16* sb2 = in_s + ((t + 3 + kd) & 3) * SLICE_HF;  // slice t-1+kd
#pragma unroll
      for (int kw = 0; kw < 3; ++kw) {
        half8 brow[8];
#pragma unroll
        for (int rr = 0; rr < 8; ++rr)
          brow[rr] = *(const half8*)(sb2 + rr * RST + cs[kw]);
#pragma unroll
        for (int kh = 0; kh < 3; ++kh) {
          const int tap = kd * 9 + kh * 3 + kw;
#pragma unroll
          for (int r = 0; r < 6; ++r)
            acc[r] = __builtin_amdgcn_mfma_f32_16x16x32_f16(
                wreg[tap], brow[r + kh], acc[r], 0, 0, 0);
        }
      }
    }

    // ---- phase B: write staged slice to ring slot (t+2)&3 ----
    if (ts < T_) {
      _Float16* dst = in_s + (ts & 3) * SLICE_HF;
#pragma unroll
      for (int k = 0; k < 32; ++k) {
        int rj = k * 8 + s_q;
        int cin = rj & 31;
        int yy = rj >> 5;
        dst[(yy * SCOLS + s_xi + 1) * PITCH + cin] = (_Float16)sv[k];
      }
#pragma unroll
      for (int j = 0; j < 2; ++j) {
        int yy = e_y4 + 4 * j;
        dst[(yy * SCOLS + 0) * PITCH + e_cin] = (_Float16)el[j];
        dst[(yy * SCOLS + 17) * PITCH + e_cin] = (_Float16)er[j];
      }
    } else if (ts == T_) {
      uint32_t* dz = (uint32_t*)(in_s + (ts & 3) * SLICE_HF);
      for (int e = tid; e < SLICE_HF / 2; e += 128) dz[e] = 0u;
    }

    // ---- gating + recurrence (packed into regs) ----
    unsigned int pk[6];
#pragma unroll
    for (int r = 0; r < 6; ++r) {
      float z0 = 1.f - 2.f / (1.f + __expf(2.f * acc[r][0]));
      float f0 = 1.f / (1.f + __expf(-acc[r][1]));
      h[r][0] = f0 * (h[r][0] - z0) + z0;
      float z1 = 1.f - 2.f / (1.f + __expf(2.f * acc[r][2]));
      float f1 = 1.f / (1.f + __expf(-acc[r][3]));
      h[r][1] = f1 * (h[r][1] - z1) + z1;
      pk[r] = packhh(h[r][0], h[r][1]);
    }
    __syncthreads();   // stage writes visible; ring slot safety

    // ---- h-stores AFTER the barrier (drain covered by next barrier) ----
#pragma unroll
    for (int r = 0; r < 6; ++r)
      gout[obase + r * W_] = pk[r];
    obase += SP_;
  }
}

// ---------------------------------------------------------------------------
// Kernel 2: per-pixel channel attention via 32x32x16 MFMA. (proven R10)
// Reads packed f16x2 h from u32-planes b*32+pr at own (y,x) tile; writes
// final f32 to planes b*32+c at the same tile -> no cross-block aliasing.
// ---------------------------------------------------------------------------
#define APIT 40
#define PSTR 1288

__global__ __launch_bounds__(512) void attn_mfma(
    unsigned int* __restrict__ g, const float* __restrict__ gamma) {
  __shared__ _Float16 qh_s[16 * PSTR];
  __shared__ _Float16 qt_s[16 * PSTR];
  __shared__ _Float16 at_s[8 * 32 * APIT];

  const int tid = threadIdx.x;
  const int x0 = blockIdx.x * 16;
  const int y = blockIdx.y;
  const int b = blockIdx.z;
  const int lane = tid & 63;
  const int wv = tid >> 6;
  const float gm = gamma[0];

  for (int e = tid; e < 16 * 16 * 31; e += 512) {
    int xi = e & 15;
    int q = e >> 4;
    int t = q % 31;
    int pr = q / 31;
    unsigned int gw = g[((size_t)(b * 32 + pr) * T_ + t) * SP_ + y * W_ + x0 + xi];
    _Float16 h0 = __builtin_bit_cast(_Float16, (unsigned short)(gw & 0xffff));
    _Float16 h1 = __builtin_bit_cast(_Float16, (unsigned short)(gw >> 16));
    int c0 = 2 * pr;
    qh_s[xi * PSTR + c0 * APIT + t] = h0;
    qh_s[xi * PSTR + (c0 + 1) * APIT + t] = h1;
    qt_s[xi * PSTR + t * APIT + c0] = h0;
    qt_s[xi * PSTR + t * APIT + c0 + 1] = h1;
  }
  qh_s[(tid & 15) * PSTR + (tid >> 4) * APIT + 31] = (_Float16)0.f;
  __syncthreads();

  const int cd = lane & 31;
  const int hi = lane >> 5;

#pragma unroll
  for (int pp = 0; pp < 2; ++pp) {
    const int px = wv * 2 + pp;
    const _Float16* qs = qh_s + px * PSTR;
    const _Float16* qt = qt_s + px * PSTR;
    _Float16* as = at_s + wv * (32 * APIT);

    half8 q0 = *(const half8*)(qs + cd * APIT + hi * 8);
    half8 q1 = *(const half8*)(qs + cd * APIT + hi * 8 + 16);
    f32x16 S = {};
    S = __builtin_amdgcn_mfma_f32_32x32x16_f16(q0, q0, S, 0, 0, 0);
    S = __builtin_amdgcn_mfma_f32_32x32x16_f16(q1, q1, S, 0, 0, 0);

    float mx = S[0];
#pragma unroll
    for (int r = 1; r < 16; ++r) mx = fmaxf(mx, S[r]);
    mx = fmaxf(mx, __shfl_xor(mx, 32));
    float sm = 0.f;
    float ev[16];
#pragma unroll
    for (int r = 0; r < 16; ++r) { ev[r] = __expf(S[r] - mx); sm += ev[r]; }
    sm += __shfl_xor(sm, 32);
    const float sc = 0.17677669529663688f / sm;

#pragma unroll
    for (int r = 0; r < 16; ++r) {
      int c = (r & 3) + 8 * (r >> 2) + 4 * hi;
      as[c * APIT + cd] = (_Float16)(ev[r] * sc);
    }

    half8 a0 = *(const half8*)(as + cd * APIT + hi * 8);
    half8 a1 = *(const half8*)(as + cd * APIT + hi * 8 + 16);
    half8 b0 = *(const half8*)(qt + cd * APIT + hi * 8);
    half8 b1 = *(const half8*)(qt + cd * APIT + hi * 8 + 16);
    f32x16 P = {};
    P = __builtin_amdgcn_mfma_f32_32x32x16_f16(a0, b0, P, 0, 0, 0);
    P = __builtin_amdgcn_mfma_f32_32x32x16_f16(a1, b1, P, 0, 0, 0);

#pragma unroll
    for (int r = 0; r < 16; ++r) {
      int c = (r & 3) + 8 * (r >> 2) + 4 * hi;
      qt_s[px * PSTR + cd * APIT + c] = (_Float16)P[r];
    }
  }
  __syncthreads();

  float* gf = (float*)g;
  for (int e = tid; e < 4 * 992; e += 512) {
    int xi4 = e & 3;
    int q = e >> 2;
    int t = q % 31;
    int c = q / 31;
    float4 rv;
#pragma unroll
    for (int j = 0; j < 4; ++j) {
      int xi = xi4 * 4 + j;
      float ah = (float)qt_s[xi * PSTR + t * APIT + c];
      float hv = (float)qh_s[xi * PSTR + c * APIT + t];
      (&rv.x)[j] = gm * ah + hv;
    }
    *(float4*)&gf[((size_t)(b * HID_ + c) * T_ + t) * SP_ + y * W_ + x0 +
                  xi4 * 4] = rv;
  }
}

// ---------------------------------------------------------------------------
extern "C" void kernel_launch(void* const* d_in, const int* in_sizes, int n_in,
                              void* d_out, int out_size, void* d_ws,
                              size_t ws_size, hipStream_t stream) {
  const float* in    = (const float*)d_in[0];  // [4,32,31,96,96]
  const float* w     = (const float*)d_in[1];  // [64,32,3,3,3]
  const float* bias  = (const float*)d_in[2];  // [64]
  const float* gamma = (const float*)d_in[3];  // [1]
  _Float16* wr = (_Float16*)d_ws;              // 110 KB fp16 fragments

  prep_w_kernel<<<216, 256, 0, stream>>>(w, wr);
  conv_rec_mfma<<<dim3(192, 4), 128, 0, stream>>>(
      in, wr, bias, (unsigned int*)d_out);
  attn_mfma<<<dim3(6, 96, 4), 512, 0, stream>>>(
      (unsigned int*)d_out, gamma);
}

// Round 17
// 357.336 us; speedup vs baseline: 1.7787x; 1.7787x over previous
//
#include <hip/hip_runtime.h>
#include <math.h>

#define B_ 4
#define CIN_ 32
#define HID_ 32
#define T_ 31
#define H_ 96
#define W_ 96
#define SP_ (H_*W_)
#define TSP (T_ * SP_)

typedef _Float16 half8 __attribute__((ext_vector_type(8)));
typedef float f32x4 __attribute__((ext_vector_type(4)));
typedef float f32x16 __attribute__((ext_vector_type(16)));

static __device__ inline unsigned int packhh(float a, float b) {
  unsigned short ua = __builtin_bit_cast(unsigned short, (_Float16)a);
  unsigned short ub = __builtin_bit_cast(unsigned short, (_Float16)b);
  return (unsigned int)ua | ((unsigned int)ub << 16);
}

// ---------------------------------------------------------------------------
// Kernel 0: weights fp32 -> fp16 gate-interleaved MFMA A-fragments.
// wr[((ocg*27 + tap)*64 + lane)*8 + i]
//   m = lane&15: gate = m&1, ch = ocg*8 + (m>>1); oc = gate*32 + ch
//   cin = (lane>>4)*8 + i
// ---------------------------------------------------------------------------
__global__ __launch_bounds__(256) void prep_w_kernel(
    const float* __restrict__ w, _Float16* __restrict__ wr) {
  int idx = blockIdx.x * 256 + threadIdx.x;
  if (idx >= 55296) return;
  int i = idx & 7;
  int lane = (idx >> 3) & 63;
  int rest = idx >> 9;             // ocg*27 + tap
  int tap = rest % 27;
  int ocg = rest / 27;
  int m = lane & 15;
  int cin = (lane >> 4) * 8 + i;
  int oc = (m & 1) * 32 + ocg * 8 + (m >> 1);
  wr[idx] = (_Float16)(w[(oc * CIN_ + cin) * 27 + tap]);
}

// ---------------------------------------------------------------------------
// Kernel 1: fused Conv3d (fp16 MFMA) + gating + SERIAL recurrence.
// R16 grid-balance design with the REGISTER CAP REMOVED:
// launch_bounds(128,1) — R16's (128,2) forced VGPR=128 < the ~150 needed
// (108 weight regs + sv[32] + acc) -> spill -> FETCH 817 MB. One change.
// block = 2 waves (128 thr) owning ONE channel-half (32 oc: ocg=half*2+wv);
// two blocks per 16x6 tile -> grid (192,4) = 768 blocks = EXACTLY 3/CU
// (even makespan; R10/R11's 384 = 1.5/CU left half the CUs idle half the
// time). LDS: 4-slot ring = 46 KB -> 3 blocks/CU = 138 KB, 6 waves/CU.
// Twin blocks duplicate staging reads (mostly L2/L3-absorbed).
// Per wave: R10's exact budget; stores after barrier; NO swizzle.
// ---------------------------------------------------------------------------
#define PITCH 40
#define SROWS 8
#define SCOLS 18
#define RST (SCOLS * PITCH)
#define SLICE_HF (SROWS * RST)             // 5760 f16 = 11520 B

__global__ __launch_bounds__(128, 1) void conv_rec_mfma(
    const float* __restrict__ in, const _Float16* __restrict__ wr,
    const float* __restrict__ bias, unsigned int* __restrict__ gout) {
  __shared__ _Float16 in_s[4 * SLICE_HF];   // 46080 B

  const int tid = threadIdx.x;
  const int bx = blockIdx.x;     // 0..191
  const int tile = bx >> 1;      // 0..95
  const int half = bx & 1;       // channel-half
  const int b = blockIdx.y;      // 0..3
  const int x0 = (tile % 6) * 16;
  const int y0 = (tile / 6) * 6;
  const int lane = tid & 63;
  const int wv = tid >> 6;       // 0..1
  const int ocg = half * 2 + wv; // 0..3 (same meaning as R10)
  const int px = lane & 15;
  const int kq = lane >> 4;      // 0..3

  // per-wave weights: 27 taps, gate-interleaved 16-slot frags (108 VGPR)
  half8 wreg[27];
  {
    const _Float16* wp = wr + (size_t)ocg * 27 * 512 + lane * 8;
#pragma unroll
    for (int tap = 0; tap < 27; ++tap)
      wreg[tap] = *(const half8*)(wp + tap * 512);
  }

  const int c0 = ocg * 8 + 2 * kq;
  f32x4 bias4;
  bias4[0] = bias[c0];
  bias4[1] = bias[32 + c0];
  bias4[2] = bias[c0 + 1];
  bias4[3] = bias[32 + c0 + 1];

  // staging roles (128 thr): interior 32 jobs (rj = k*8 + s_q -> 8r x 32cin);
  // edges: e_cin = tid&31, rows e_y4 and e_y4+4.
  const int s_xi = tid & 15;
  const int s_q  = tid >> 4;       // 0..7
  const int e_cin = tid & 31;
  const int e_y4  = tid >> 5;      // 0..3
  const bool has_l = (x0 > 0), has_r = (x0 + 16 < W_);

  const float* inb = in + (size_t)(b * CIN_) * TSP;

  auto stage_full = [&](int ts) {   // prologue only
    _Float16* dst = in_s + (ts & 3) * SLICE_HF;
    const int tso = ts * SP_;
#pragma unroll
    for (int k = 0; k < 32; ++k) {
      int rj = k * 8 + s_q;
      int cin = rj & 31;
      int yy = rj >> 5;
      int gy = y0 - 1 + yy;
      float v = 0.f;
      if ((unsigned)gy < (unsigned)H_)
        v = inb[(size_t)cin * TSP + tso + gy * W_ + x0 + s_xi];
      dst[(yy * SCOLS + s_xi + 1) * PITCH + cin] = (_Float16)v;
    }
#pragma unroll
    for (int j = 0; j < 2; ++j) {
      int yy = e_y4 + 4 * j;
      int gy = y0 - 1 + yy;
      float vl = 0.f, vr = 0.f;
      if ((unsigned)gy < (unsigned)H_) {
        const float* rb = inb + (size_t)e_cin * TSP + tso + gy * W_;
        if (has_l) vl = rb[x0 - 1];
        if (has_r) vr = rb[x0 + 16];
      }
      dst[(yy * SCOLS + 0) * PITCH + e_cin] = (_Float16)vl;
      dst[(yy * SCOLS + 17) * PITCH + e_cin] = (_Float16)vr;
    }
  };

  // prologue: slot 3 = slice -1 = zeros; slices 0,1 staged
  {
    uint32_t* dz = (uint32_t*)(in_s + 3 * SLICE_HF);
    for (int e = tid; e < SLICE_HF / 2; e += 128) dz[e] = 0u;
  }
  stage_full(0);
  stage_full(1);
  __syncthreads();

  float h[6][2];
#pragma unroll
  for (int r = 0; r < 6; ++r) { h[r][0] = 0.f; h[r][1] = 0.f; }

  const int pr = ocg * 4 + kq;   // packed pair plane 0..15
  size_t obase = ((size_t)(b * 32 + pr) * T_) * SP_ + y0 * W_ + x0 + px;

  // brow column offsets (no swizzle)
  int cs[3];
#pragma unroll
  for (int kw = 0; kw < 3; ++kw) cs[kw] = (px + kw) * PITCH + kq * 8;

  for (int t = 0; t < T_; ++t) {
    const int ts = t + 2;

    // ---- phase A: issue stage loads for slice ts (held in regs) ----
    float sv[32], el[2] = {0.f, 0.f}, er[2] = {0.f, 0.f};
    if (ts < T_) {
      const int tso = ts * SP_;
#pragma unroll
      for (int k = 0; k < 32; ++k) {
        int rj = k * 8 + s_q;
        int cin = rj & 31;
        int yy = rj >> 5;
        int gy = y0 - 1 + yy;
        sv[k] = 0.f;
        if ((unsigned)gy < (unsigned)H_)
          sv[k] = inb[(size_t)cin * TSP + tso + gy * W_ + x0 + s_xi];
      }
#pragma unroll
      for (int j = 0; j < 2; ++j) {
        int gy = y0 - 1 + e_y4 + 4 * j;
        if ((unsigned)gy < (unsigned)H_) {
          const float* rb = inb + (size_t)e_cin * TSP + tso + gy * W_;
          if (has_l) el[j] = rb[x0 - 1];
          if (has_r) er[j] = rb[x0 + 16];
        }
      }
    }

    // ---- compute: 27 taps x 6 rows (R10 body, unchanged) ----
    f32x4 acc[6];
#pragma unroll
    for (int r = 0; r < 6; ++r) acc[r] = bias4;

#pragma unroll
    for (int kd = 0; kd < 3; ++kd) {
      const _Float16* sb2 = in_s + ((t + 3 + kd) & 3) * SLICE_HF;  // slice t-1+kd
#pragma unroll
      for (int kw = 0; kw < 3; ++kw) {
        half8 brow[8];
#pragma unroll
        for (int rr = 0; rr < 8; ++rr)
          brow[rr] = *(const half8*)(sb2 + rr * RST + cs[kw]);
#pragma unroll
        for (int kh = 0; kh < 3; ++kh) {
          const int tap = kd * 9 + kh * 3 + kw;
#pragma unroll
          for (int r = 0; r < 6; ++r)
            acc[r] = __builtin_amdgcn_mfma_f32_16x16x32_f16(
                wreg[tap], brow[r + kh], acc[r], 0, 0, 0);
        }
      }
    }

    // ---- phase B: write staged slice to ring slot (t+2)&3 ----
    if (ts < T_) {
      _Float16* dst = in_s + (ts & 3) * SLICE_HF;
#pragma unroll
      for (int k = 0; k < 32; ++k) {
        int rj = k * 8 + s_q;
        int cin = rj & 31;
        int yy = rj >> 5;
        dst[(yy * SCOLS + s_xi + 1) * PITCH + cin] = (_Float16)sv[k];
      }
#pragma unroll
      for (int j = 0; j < 2; ++j) {
        int yy = e_y4 + 4 * j;
        dst[(yy * SCOLS + 0) * PITCH + e_cin] = (_Float16)el[j];
        dst[(yy * SCOLS + 17) * PITCH + e_cin] = (_Float16)er[j];
      }
    } else if (ts == T_) {
      uint32_t* dz = (uint32_t*)(in_s + (ts & 3) * SLICE_HF);
      for (int e = tid; e < SLICE_HF / 2; e += 128) dz[e] = 0u;
    }

    // ---- gating + recurrence (packed into regs) ----
    unsigned int pk[6];
#pragma unroll
    for (int r = 0; r < 6; ++r) {
      float z0 = 1.f - 2.f / (1.f + __expf(2.f * acc[r][0]));
      float f0 = 1.f / (1.f + __expf(-acc[r][1]));
      h[r][0] = f0 * (h[r][0] - z0) + z0;
      float z1 = 1.f - 2.f / (1.f + __expf(2.f * acc[r][2]));
      float f1 = 1.f / (1.f + __expf(-acc[r][3]));
      h[r][1] = f1 * (h[r][1] - z1) + z1;
      pk[r] = packhh(h[r][0], h[r][1]);
    }
    __syncthreads();   // stage writes visible; ring slot safety

    // ---- h-stores AFTER the barrier (drain covered by next barrier) ----
#pragma unroll
    for (int r = 0; r < 6; ++r)
      gout[obase + r * W_] = pk[r];
    obase += SP_;
  }
}

// ---------------------------------------------------------------------------
// Kernel 2: per-pixel channel attention via 32x32x16 MFMA. (proven R10)
// Reads packed f16x2 h from u32-planes b*32+pr at own (y,x) tile; writes
// final f32 to planes b*32+c at the same tile -> no cross-block aliasing.
// ---------------------------------------------------------------------------
#define APIT 40
#define PSTR 1288

__global__ __launch_bounds__(512) void attn_mfma(
    unsigned int* __restrict__ g, const float* __restrict__ gamma) {
  __shared__ _Float16 qh_s[16 * PSTR];
  __shared__ _Float16 qt_s[16 * PSTR];
  __shared__ _Float16 at_s[8 * 32 * APIT];

  const int tid = threadIdx.x;
  const int x0 = blockIdx.x * 16;
  const int y = blockIdx.y;
  const int b = blockIdx.z;
  const int lane = tid & 63;
  const int wv = tid >> 6;
  const float gm = gamma[0];

  for (int e = tid; e < 16 * 16 * 31; e += 512) {
    int xi = e & 15;
    int q = e >> 4;
    int t = q % 31;
    int pr = q / 31;
    unsigned int gw = g[((size_t)(b * 32 + pr) * T_ + t) * SP_ + y * W_ + x0 + xi];
    _Float16 h0 = __builtin_bit_cast(_Float16, (unsigned short)(gw & 0xffff));
    _Float16 h1 = __builtin_bit_cast(_Float16, (unsigned short)(gw >> 16));
    int c0 = 2 * pr;
    qh_s[xi * PSTR + c0 * APIT + t] = h0;
    qh_s[xi * PSTR + (c0 + 1) * APIT + t] = h1;
    qt_s[xi * PSTR + t * APIT + c0] = h0;
    qt_s[xi * PSTR + t * APIT + c0 + 1] = h1;
  }
  qh_s[(tid & 15) * PSTR + (tid >> 4) * APIT + 31] = (_Float16)0.f;
  __syncthreads();

  const int cd = lane & 31;
  const int hi = lane >> 5;

#pragma unroll
  for (int pp = 0; pp < 2; ++pp) {
    const int px = wv * 2 + pp;
    const _Float16* qs = qh_s + px * PSTR;
    const _Float16* qt = qt_s + px * PSTR;
    _Float16* as = at_s + wv * (32 * APIT);

    half8 q0 = *(const half8*)(qs + cd * APIT + hi * 8);
    half8 q1 = *(const half8*)(qs + cd * APIT + hi * 8 + 16);
    f32x16 S = {};
    S = __builtin_amdgcn_mfma_f32_32x32x16_f16(q0, q0, S, 0, 0, 0);
    S = __builtin_amdgcn_mfma_f32_32x32x16_f16(q1, q1, S, 0, 0, 0);

    float mx = S[0];
#pragma unroll
    for (int r = 1; r < 16; ++r) mx = fmaxf(mx, S[r]);
    mx = fmaxf(mx, __shfl_xor(mx, 32));
    float sm = 0.f;
    float ev[16];
#pragma unroll
    for (int r = 0; r < 16; ++r) { ev[r] = __expf(S[r] - mx); sm += ev[r]; }
    sm += __shfl_xor(sm, 32);
    const float sc = 0.17677669529663688f / sm;

#pragma unroll
    for (int r = 0; r < 16; ++r) {
      int c = (r & 3) + 8 * (r >> 2) + 4 * hi;
      as[c * APIT + cd] = (_Float16)(ev[r] * sc);
    }

    half8 a0 = *(const half8*)(as + cd * APIT + hi * 8);
    half8 a1 = *(const half8*)(as + cd * APIT + hi * 8 + 16);
    half8 b0 = *(const half8*)(qt + cd * APIT + hi * 8);
    half8 b1 = *(const half8*)(qt + cd * APIT + hi * 8 + 16);
    f32x16 P = {};
    P = __builtin_amdgcn_mfma_f32_32x32x16_f16(a0, b0, P, 0, 0, 0);
    P = __builtin_amdgcn_mfma_f32_32x32x16_f16(a1, b1, P, 0, 0, 0);

#pragma unroll
    for (int r = 0; r < 16; ++r) {
      int c = (r & 3) + 8 * (r >> 2) + 4 * hi;
      qt_s[px * PSTR + cd * APIT + c] = (_Float16)P[r];
    }
  }
  __syncthreads();

  float* gf = (float*)g;
  for (int e = tid; e < 4 * 992; e += 512) {
    int xi4 = e & 3;
    int q = e >> 2;
    int t = q % 31;
    int c = q / 31;
    float4 rv;
#pragma unroll
    for (int j = 0; j < 4; ++j) {
      int xi = xi4 * 4 + j;
      float ah = (float)qt_s[xi * PSTR + t * APIT + c];
      float hv = (float)qh_s[xi * PSTR + c * APIT + t];
      (&rv.x)[j] = gm * ah + hv;
    }
    *(float4*)&gf[((size_t)(b * HID_ + c) * T_ + t) * SP_ + y * W_ + x0 +
                  xi4 * 4] = rv;
  }
}

// ---------------------------------------------------------------------------
extern "C" void kernel_launch(void* const* d_in, const int* in_sizes, int n_in,
                              void* d_out, int out_size, void* d_ws,
                              size_t ws_size, hipStream_t stream) {
  const float* in    = (const float*)d_in[0];  // [4,32,31,96,96]
  const float* w     = (const float*)d_in[1];  // [64,32,3,3,3]
  const float* bias  = (const float*)d_in[2];  // [64]
  const float* gamma = (const float*)d_in[3];  // [1]
  _Float16* wr = (_Float16*)d_ws;              // 110 KB fp16 fragments

  prep_w_kernel<<<216, 256, 0, stream>>>(w, wr);
  conv_rec_mfma<<<dim3(192, 4), 128, 0, stream>>>(
      in, wr, bias, (unsigned int*)d_out);
  attn_mfma<<<dim3(6, 96, 4), 512, 0, stream>>>(
      (unsigned int*)d_out, gamma);
}

// Round 18
// 282.347 us; speedup vs baseline: 2.2511x; 1.2656x over previous
//
#include <hip/hip_runtime.h>
#include <math.h>

#define B_ 4
#define CIN_ 32
#define HID_ 32
#define T_ 31
#define H_ 96
#define W_ 96
#define SP_ (H_*W_)
#define TSP (T_ * SP_)

typedef _Float16 half8 __attribute__((ext_vector_type(8)));
typedef float f32x4 __attribute__((ext_vector_type(4)));
typedef float f32x16 __attribute__((ext_vector_type(16)));

static __device__ inline unsigned int packhh(float a, float b) {
  unsigned short ua = __builtin_bit_cast(unsigned short, (_Float16)a);
  unsigned short ub = __builtin_bit_cast(unsigned short, (_Float16)b);
  return (unsigned int)ua | ((unsigned int)ub << 16);
}

// ---------------------------------------------------------------------------
// Kernel 0: weights fp32 -> fp16 gate-interleaved MFMA A-fragments.
// wr[((ocg*27 + tap)*64 + lane)*8 + i]
//   m = lane&15: gate = m&1, ch = ocg*8 + (m>>1); oc = gate*32 + ch
//   cin = (lane>>4)*8 + i
// ---------------------------------------------------------------------------
__global__ __launch_bounds__(256) void prep_w_kernel(
    const float* __restrict__ w, _Float16* __restrict__ wr) {
  int idx = blockIdx.x * 256 + threadIdx.x;
  if (idx >= 55296) return;
  int i = idx & 7;
  int lane = (idx >> 3) & 63;
  int rest = idx >> 9;             // ocg*27 + tap
  int tap = rest % 27;
  int ocg = rest / 27;
  int m = lane & 15;
  int cin = (lane >> 4) * 8 + i;
  int oc = (m & 1) * 32 + ocg * 8 + (m >> 1);
  wr[idx] = (_Float16)(w[(oc * CIN_ + cin) * 27 + tap]);
}

// ---------------------------------------------------------------------------
// Kernel 1: fused Conv3d (fp16 MFMA) + gating + SERIAL time recurrence.
// == R11 (best measured: 210us) MINUS the swizzle (which doubled bank
// conflicts to 2.9e7). Keeps: 4 waves x 16 oc-slots, tile 16x6, grid 96x4,
// in-VGPR weights (108/wave), hoisted staging addressing, packed fp16x2 h
// output, stores AFTER the barrier. 4-slot ring, 46 KB, 2 blocks/CU.
// Conv structure is FINAL per R7-R17 experiments (7 restructures all lost).
// ---------------------------------------------------------------------------
#define PITCH 40
#define SROWS 8
#define SCOLS 18
#define RST (SCOLS * PITCH)                // 720 halfs per LDS row
#define SLICE_HF (SROWS * RST)             // 5760 f16 = 11520 B

__global__ __launch_bounds__(256, 2) void conv_rec_mfma(
    const float* __restrict__ in, const _Float16* __restrict__ wr,
    const float* __restrict__ bias, unsigned int* __restrict__ gout) {
  __shared__ _Float16 in_s[4 * SLICE_HF];   // 46080 B

  const int tid = threadIdx.x;
  const int tile = blockIdx.x;   // 0..95
  const int b = blockIdx.y;      // 0..3
  const int x0 = (tile % 6) * 16;
  const int y0 = (tile / 6) * 6;
  const int lane = tid & 63;
  const int ocg = tid >> 6;      // 0..3
  const int px = lane & 15;
  const int kq = lane >> 4;      // 0..3

  // per-wave weights: 27 taps, gate-interleaved 16-slot frags (108 VGPR)
  half8 wreg[27];
  {
    const _Float16* wp = wr + (size_t)ocg * 27 * 512 + lane * 8;
#pragma unroll
    for (int tap = 0; tap < 27; ++tap)
      wreg[tap] = *(const half8*)(wp + tap * 512);
  }

  const int c0 = ocg * 8 + 2 * kq;
  f32x4 bias4;
  bias4[0] = bias[c0];
  bias4[1] = bias[32 + c0];
  bias4[2] = bias[c0 + 1];
  bias4[3] = bias[32 + c0 + 1];

  // ---- staging thread-const bases (hoisted; no div/mod in loop) ----
  const int s_xi = tid & 15;
  const int s_q  = tid >> 4;       // 0..15
  // interior: job k -> yy = k>>1, cin = (k&1)*16 + s_q, col = s_xi+1
  const int ibase = s_q * TSP + (y0 - 1) * W_ + x0 + s_xi;
  const int wbase = (s_xi + 1) * PITCH + s_q;
  // edges: lane -> (e_yy = tid>>5, e_cin = tid&31), cols 0 and 17
  const int e_cin = tid & 31;
  const int e_yy  = tid >> 5;
  const int e_gy  = y0 - 1 + e_yy;
  const bool e_ok = ((unsigned)e_gy < (unsigned)H_);
  const int eoff  = e_cin * TSP + e_gy * W_;
  const int ew0   = e_yy * RST + 0 * PITCH + e_cin;
  const int ew1   = e_yy * RST + 17 * PITCH + e_cin;
  const bool has_l = (x0 > 0), has_r = (x0 + 16 < W_);

  // brow column offsets — NO swizzle (R11's swizzle measured harmful)
  int cs[3];
#pragma unroll
  for (int kw = 0; kw < 3; ++kw) cs[kw] = (px + kw) * PITCH + kq * 8;

  const float* inb = in + (size_t)(b * CIN_) * TSP;

  auto stage_full = [&](int ts) {   // prologue only
    _Float16* dst = in_s + (ts & 3) * SLICE_HF;
    const int tso = ts * SP_;
#pragma unroll
    for (int k = 0; k < 16; ++k) {
      const int gy = y0 - 1 + (k >> 1);       // wave-uniform validity
      float v = 0.f;
      if ((unsigned)gy < (unsigned)H_)
        v = inb[ibase + (k & 1) * 16 * TSP + (k >> 1) * W_ + tso];
      dst[wbase + (k >> 1) * RST + (k & 1) * 16] = (_Float16)v;
    }
    float v0 = 0.f, v1 = 0.f;
    if (e_ok) {
      if (has_l) v0 = inb[eoff + tso + x0 - 1];
      if (has_r) v1 = inb[eoff + tso + x0 + 16];
    }
    dst[ew0] = (_Float16)v0;
    dst[ew1] = (_Float16)v1;
  };

  // prologue: slot 3 = slice -1 = zeros (single pass); slices 0,1 staged
  {
    uint32_t* dz = (uint32_t*)(in_s + 3 * SLICE_HF);
    for (int e = tid; e < SLICE_HF / 2; e += 256) dz[e] = 0u;
  }
  stage_full(0);
  stage_full(1);
  __syncthreads();

  float h[6][2];
#pragma unroll
  for (int r = 0; r < 6; ++r) { h[r][0] = 0.f; h[r][1] = 0.f; }

  const int pr = ocg * 4 + kq;   // packed pair plane 0..15
  size_t obase = ((size_t)(b * 32 + pr) * T_) * SP_ + y0 * W_ + x0 + px;

  for (int t = 0; t < T_; ++t) {
    const int ts = t + 2;

    // ---- phase A: issue stage loads for slice ts (held in regs) ----
    float sv[16], ev0 = 0.f, ev1 = 0.f;
    if (ts < T_) {
      const int tso = ts * SP_;
#pragma unroll
      for (int k = 0; k < 16; ++k) {
        const int gy = y0 - 1 + (k >> 1);
        sv[k] = 0.f;
        if ((unsigned)gy < (unsigned)H_)
          sv[k] = inb[ibase + (k & 1) * 16 * TSP + (k >> 1) * W_ + tso];
      }
      if (e_ok) {
        if (has_l) ev0 = inb[eoff + tso + x0 - 1];
        if (has_r) ev1 = inb[eoff + tso + x0 + 16];
      }
    }

    // ---- compute: 27 taps x 6 rows ----
    f32x4 acc[6];
#pragma unroll
    for (int r = 0; r < 6; ++r) acc[r] = bias4;

#pragma unroll
    for (int kd = 0; kd < 3; ++kd) {
      const _Float16* sb2 = in_s + ((t + 3 + kd) & 3) * SLICE_HF;  // slice t-1+kd
#pragma unroll
      for (int kw = 0; kw < 3; ++kw) {
        half8 brow[8];
#pragma unroll
        for (int rr = 0; rr < 8; ++rr)
          brow[rr] = *(const half8*)(sb2 + rr * RST + cs[kw]);
#pragma unroll
        for (int kh = 0; kh < 3; ++kh) {
          const int tap = kd * 9 + kh * 3 + kw;
#pragma unroll
          for (int r = 0; r < 6; ++r)
            acc[r] = __builtin_amdgcn_mfma_f32_16x16x32_f16(
                wreg[tap], brow[r + kh], acc[r], 0, 0, 0);
        }
      }
    }

    // ---- phase B: write staged slice to ring slot (t+2)&3 ----
    if (ts < T_) {
      _Float16* dst = in_s + (ts & 3) * SLICE_HF;
#pragma unroll
      for (int k = 0; k < 16; ++k)
        dst[wbase + (k >> 1) * RST + (k & 1) * 16] = (_Float16)sv[k];
      dst[ew0] = (_Float16)ev0;
      dst[ew1] = (_Float16)ev1;
    } else if (ts == T_) {
      uint32_t* dz = (uint32_t*)(in_s + (ts & 3) * SLICE_HF);
      for (int e = tid; e < SLICE_HF / 2; e += 256) dz[e] = 0u;
    }

    // ---- gating + recurrence (packed into regs) ----
    unsigned int pk[6];
#pragma unroll
    for (int r = 0; r < 6; ++r) {
      float z0 = 1.f - 2.f / (1.f + __expf(2.f * acc[r][0]));
      float f0 = 1.f / (1.f + __expf(-acc[r][1]));
      h[r][0] = f0 * (h[r][0] - z0) + z0;
      float z1 = 1.f - 2.f / (1.f + __expf(2.f * acc[r][2]));
      float f1 = 1.f / (1.f + __expf(-acc[r][3]));
      h[r][1] = f1 * (h[r][1] - z1) + z1;
      pk[r] = packhh(h[r][0], h[r][1]);
    }
    __syncthreads();   // stage writes visible; ring slot safety

    // ---- h-stores AFTER the barrier (drain covered by next barrier) ----
#pragma unroll
    for (int r = 0; r < 6; ++r)
      gout[obase + r * W_] = pk[r];
    obase += SP_;
  }
}

// ---------------------------------------------------------------------------
// Kernel 2: per-pixel channel attention via 32x32x16 MFMA.
// PX=8, 256 thr (4 waves, 2 px/wave), LDS 51.5 KB -> 3 blocks/CU (was 1):
// inter-block overlap hides global-load staging under other blocks' MFMA.
// Reads packed f16x2 h from u32-planes b*32+pr at own (y,x) tile; writes
// final f32 to planes b*32+c at the same tile -> no cross-block aliasing.
// ---------------------------------------------------------------------------
#define APIT 40
#define PSTR 1288

__global__ __launch_bounds__(256) void attn_mfma(
    unsigned int* __restrict__ g, const float* __restrict__ gamma) {
  __shared__ _Float16 qh_s[8 * PSTR];       // 20608 B
  __shared__ _Float16 qt_s[8 * PSTR];       // 20608 B
  __shared__ _Float16 at_s[4 * 32 * APIT];  // 10240 B

  const int tid = threadIdx.x;
  const int x0 = blockIdx.x * 8;
  const int y = blockIdx.y;
  const int b = blockIdx.z;
  const int lane = tid & 63;
  const int wv = tid >> 6;       // 0..3
  const float gm = gamma[0];

  // stage packed h: 8 px x 16 pairs x 31 t u32 reads (32B runs), unpack
  for (int e = tid; e < 8 * 16 * 31; e += 256) {
    int xi = e & 7;
    int q = e >> 3;
    int t = q % 31;
    int pr = q / 31;
    unsigned int gw = g[((size_t)(b * 32 + pr) * T_ + t) * SP_ + y * W_ + x0 + xi];
    _Float16 h0 = __builtin_bit_cast(_Float16, (unsigned short)(gw & 0xffff));
    _Float16 h1 = __builtin_bit_cast(_Float16, (unsigned short)(gw >> 16));
    int c0 = 2 * pr;
    qh_s[xi * PSTR + c0 * APIT + t] = h0;
    qh_s[xi * PSTR + (c0 + 1) * APIT + t] = h1;
    qt_s[xi * PSTR + t * APIT + c0] = h0;
    qt_s[xi * PSTR + t * APIT + c0 + 1] = h1;
  }
  // zero-pad t=31 of qh (8 px x 32 c = 256 elems, 1/thread)
  qh_s[(tid & 7) * PSTR + (tid >> 3) * APIT + 31] = (_Float16)0.f;
  __syncthreads();

  const int cd = lane & 31;
  const int hi = lane >> 5;

#pragma unroll
  for (int pp = 0; pp < 2; ++pp) {
    const int px = wv * 2 + pp;
    const _Float16* qs = qh_s + px * PSTR;
    const _Float16* qt = qt_s + px * PSTR;
    _Float16* as = at_s + wv * (32 * APIT);

    // QK^T: S[c][d] = sum_t qh[c][t] qh[d][t]
    half8 q0 = *(const half8*)(qs + cd * APIT + hi * 8);
    half8 q1 = *(const half8*)(qs + cd * APIT + hi * 8 + 16);
    f32x16 S = {};
    S = __builtin_amdgcn_mfma_f32_32x32x16_f16(q0, q0, S, 0, 0, 0);
    S = __builtin_amdgcn_mfma_f32_32x32x16_f16(q1, q1, S, 0, 0, 0);

    // softmax over c (rows in regs + lane^32), then * 1/sqrt(32)
    float mx = S[0];
#pragma unroll
    for (int r = 1; r < 16; ++r) mx = fmaxf(mx, S[r]);
    mx = fmaxf(mx, __shfl_xor(mx, 32));
    float sm = 0.f;
    float ev[16];
#pragma unroll
    for (int r = 0; r < 16; ++r) { ev[r] = __expf(S[r] - mx); sm += ev[r]; }
    sm += __shfl_xor(sm, 32);
    const float sc = 0.17677669529663688f / sm;

#pragma unroll
    for (int r = 0; r < 16; ++r) {
      int c = (r & 3) + 8 * (r >> 2) + 4 * hi;
      as[c * APIT + cd] = (_Float16)(ev[r] * sc);
    }

    // PV: P[c][t] = sum_d attn[c][d] qh[d][t]
    half8 a0 = *(const half8*)(as + cd * APIT + hi * 8);
    half8 a1 = *(const half8*)(as + cd * APIT + hi * 8 + 16);
    half8 b0 = *(const half8*)(qt + cd * APIT + hi * 8);
    half8 b1 = *(const half8*)(qt + cd * APIT + hi * 8 + 16);
    f32x16 P = {};
    P = __builtin_amdgcn_mfma_f32_32x32x16_f16(a0, b0, P, 0, 0, 0);
    P = __builtin_amdgcn_mfma_f32_32x32x16_f16(a1, b1, P, 0, 0, 0);

    // result (lane holds t = cd, c in regs) -> qt[t*APIT + c]
#pragma unroll
    for (int r = 0; r < 16; ++r) {
      int c = (r & 3) + 8 * (r >> 2) + 4 * hi;
      qt_s[px * PSTR + cd * APIT + c] = (_Float16)P[r];
    }
  }
  __syncthreads();

  // store: out = gamma * ah + h (float4 writes, 2 per (c,t))
  float* gf = (float*)g;
  for (int e = tid; e < 2 * 992; e += 256) {
    int xi4 = e & 1;
    int q = e >> 1;
    int t = q % 31;
    int c = q / 31;
    float4 rv;
#pragma unroll
    for (int j = 0; j < 4; ++j) {
      int xi = xi4 * 4 + j;
      float ah = (float)qt_s[xi * PSTR + t * APIT + c];
      float hv = (float)qh_s[xi * PSTR + c * APIT + t];
      (&rv.x)[j] = gm * ah + hv;
    }
    *(float4*)&gf[((size_t)(b * HID_ + c) * T_ + t) * SP_ + y * W_ + x0 +
                  xi4 * 4] = rv;
  }
}

// ---------------------------------------------------------------------------
extern "C" void kernel_launch(void* const* d_in, const int* in_sizes, int n_in,
                              void* d_out, int out_size, void* d_ws,
                              size_t ws_size, hipStream_t stream) {
  const float* in    = (const float*)d_in[0];  // [4,32,31,96,96]
  const float* w     = (const float*)d_in[1];  // [64,32,3,3,3]
  const float* bias  = (const float*)d_in[2];  // [64]
  const float* gamma = (const float*)d_in[3];  // [1]
  _Float16* wr = (_Float16*)d_ws;              // 110 KB fp16 fragments

  prep_w_kernel<<<216, 256, 0, stream>>>(w, wr);
  conv_rec_mfma<<<dim3(96, 4), 256, 0, stream>>>(
      in, wr, bias, (unsigned int*)d_out);
  attn_mfma<<<dim3(12, 96, 4), 256, 0, stream>>>(
      (unsigned int*)d_out, gamma);
}

// Round 19
// 270.250 us; speedup vs baseline: 2.3519x; 1.0448x over previous
//
#include <hip/hip_runtime.h>
#include <math.h>

#define B_ 4
#define CIN_ 32
#define HID_ 32
#define T_ 31
#define H_ 96
#define W_ 96
#define SP_ (H_*W_)
#define TSP (T_ * SP_)

typedef _Float16 half8 __attribute__((ext_vector_type(8)));
typedef float f32x4 __attribute__((ext_vector_type(4)));
typedef float f32x16 __attribute__((ext_vector_type(16)));

static __device__ inline unsigned int packhh(float a, float b) {
  unsigned short ua = __builtin_bit_cast(unsigned short, (_Float16)a);
  unsigned short ub = __builtin_bit_cast(unsigned short, (_Float16)b);
  return (unsigned int)ua | ((unsigned int)ub << 16);
}

// ---------------------------------------------------------------------------
// Kernel 0: weights fp32 -> fp16 gate-interleaved MFMA A-fragments.
// wr[((ocg*27 + tap)*64 + lane)*8 + i]
//   m = lane&15: gate = m&1, ch = ocg*8 + (m>>1); oc = gate*32 + ch
//   cin = (lane>>4)*8 + i
// ---------------------------------------------------------------------------
__global__ __launch_bounds__(256) void prep_w_kernel(
    const float* __restrict__ w, _Float16* __restrict__ wr) {
  int idx = blockIdx.x * 256 + threadIdx.x;
  if (idx >= 55296) return;
  int i = idx & 7;
  int lane = (idx >> 3) & 63;
  int rest = idx >> 9;             // ocg*27 + tap
  int tap = rest % 27;
  int ocg = rest / 27;
  int m = lane & 15;
  int cin = (lane >> 4) * 8 + i;
  int oc = (m & 1) * 32 + ocg * 8 + (m >> 1);
  wr[idx] = (_Float16)(w[(oc * CIN_ + cin) * 27 + tap]);
}

// ---------------------------------------------------------------------------
// Kernel 1: fused Conv3d (fp16 MFMA) + gating + SERIAL time recurrence.
// == R18 verbatim (best measured: 198us). R11 minus swizzle: 4 waves x 16
// oc-slots, tile 16x6, grid 96x4, in-VGPR weights (108/wave), hoisted
// staging addressing, packed fp16x2 h output, stores AFTER the barrier.
// 4-slot ring, 46 KB, 2 blocks/CU. FINAL per R7-R17 (7 restructures lost).
// ---------------------------------------------------------------------------
#define PITCH 40
#define SROWS 8
#define SCOLS 18
#define RST (SCOLS * PITCH)                // 720 halfs per LDS row
#define SLICE_HF (SROWS * RST)             // 5760 f16 = 11520 B

__global__ __launch_bounds__(256, 2) void conv_rec_mfma(
    const float* __restrict__ in, const _Float16* __restrict__ wr,
    const float* __restrict__ bias, unsigned int* __restrict__ gout) {
  __shared__ _Float16 in_s[4 * SLICE_HF];   // 46080 B

  const int tid = threadIdx.x;
  const int tile = blockIdx.x;   // 0..95
  const int b = blockIdx.y;      // 0..3
  const int x0 = (tile % 6) * 16;
  const int y0 = (tile / 6) * 6;
  const int lane = tid & 63;
  const int ocg = tid >> 6;      // 0..3
  const int px = lane & 15;
  const int kq = lane >> 4;      // 0..3

  // per-wave weights: 27 taps, gate-interleaved 16-slot frags (108 VGPR)
  half8 wreg[27];
  {
    const _Float16* wp = wr + (size_t)ocg * 27 * 512 + lane * 8;
#pragma unroll
    for (int tap = 0; tap < 27; ++tap)
      wreg[tap] = *(const half8*)(wp + tap * 512);
  }

  const int c0 = ocg * 8 + 2 * kq;
  f32x4 bias4;
  bias4[0] = bias[c0];
  bias4[1] = bias[32 + c0];
  bias4[2] = bias[c0 + 1];
  bias4[3] = bias[32 + c0 + 1];

  // ---- staging thread-const bases (hoisted; no div/mod in loop) ----
  const int s_xi = tid & 15;
  const int s_q  = tid >> 4;       // 0..15
  const int ibase = s_q * TSP + (y0 - 1) * W_ + x0 + s_xi;
  const int wbase = (s_xi + 1) * PITCH + s_q;
  const int e_cin = tid & 31;
  const int e_yy  = tid >> 5;
  const int e_gy  = y0 - 1 + e_yy;
  const bool e_ok = ((unsigned)e_gy < (unsigned)H_);
  const int eoff  = e_cin * TSP + e_gy * W_;
  const int ew0   = e_yy * RST + 0 * PITCH + e_cin;
  const int ew1   = e_yy * RST + 17 * PITCH + e_cin;
  const bool has_l = (x0 > 0), has_r = (x0 + 16 < W_);

  // brow column offsets — NO swizzle
  int cs[3];
#pragma unroll
  for (int kw = 0; kw < 3; ++kw) cs[kw] = (px + kw) * PITCH + kq * 8;

  const float* inb = in + (size_t)(b * CIN_) * TSP;

  auto stage_full = [&](int ts) {   // prologue only
    _Float16* dst = in_s + (ts & 3) * SLICE_HF;
    const int tso = ts * SP_;
#pragma unroll
    for (int k = 0; k < 16; ++k) {
      const int gy = y0 - 1 + (k >> 1);       // wave-uniform validity
      float v = 0.f;
      if ((unsigned)gy < (unsigned)H_)
        v = inb[ibase + (k & 1) * 16 * TSP + (k >> 1) * W_ + tso];
      dst[wbase + (k >> 1) * RST + (k & 1) * 16] = (_Float16)v;
    }
    float v0 = 0.f, v1 = 0.f;
    if (e_ok) {
      if (has_l) v0 = inb[eoff + tso + x0 - 1];
      if (has_r) v1 = inb[eoff + tso + x0 + 16];
    }
    dst[ew0] = (_Float16)v0;
    dst[ew1] = (_Float16)v1;
  };

  // prologue: slot 3 = slice -1 = zeros (single pass); slices 0,1 staged
  {
    uint32_t* dz = (uint32_t*)(in_s + 3 * SLICE_HF);
    for (int e = tid; e < SLICE_HF / 2; e += 256) dz[e] = 0u;
  }
  stage_full(0);
  stage_full(1);
  __syncthreads();

  float h[6][2];
#pragma unroll
  for (int r = 0; r < 6; ++r) { h[r][0] = 0.f; h[r][1] = 0.f; }

  const int pr = ocg * 4 + kq;   // packed pair plane 0..15
  size_t obase = ((size_t)(b * 32 + pr) * T_) * SP_ + y0 * W_ + x0 + px;

  for (int t = 0; t < T_; ++t) {
    const int ts = t + 2;

    // ---- phase A: issue stage loads for slice ts (held in regs) ----
    float sv[16], ev0 = 0.f, ev1 = 0.f;
    if (ts < T_) {
      const int tso = ts * SP_;
#pragma unroll
      for (int k = 0; k < 16; ++k) {
        const int gy = y0 - 1 + (k >> 1);
        sv[k] = 0.f;
        if ((unsigned)gy < (unsigned)H_)
          sv[k] = inb[ibase + (k & 1) * 16 * TSP + (k >> 1) * W_ + tso];
      }
      if (e_ok) {
        if (has_l) ev0 = inb[eoff + tso + x0 - 1];
        if (has_r) ev1 = inb[eoff + tso + x0 + 16];
      }
    }

    // ---- compute: 27 taps x 6 rows ----
    f32x4 acc[6];
#pragma unroll
    for (int r = 0; r < 6; ++r) acc[r] = bias4;

#pragma unroll
    for (int kd = 0; kd < 3; ++kd) {
      const _Float16* sb2 = in_s + ((t + 3 + kd) & 3) * SLICE_HF;  // slice t-1+kd
#pragma unroll
      for (int kw = 0; kw < 3; ++kw) {
        half8 brow[8];
#pragma unroll
        for (int rr = 0; rr < 8; ++rr)
          brow[rr] = *(const half8*)(sb2 + rr * RST + cs[kw]);
#pragma unroll
        for (int kh = 0; kh < 3; ++kh) {
          const int tap = kd * 9 + kh * 3 + kw;
#pragma unroll
          for (int r = 0; r < 6; ++r)
            acc[r] = __builtin_amdgcn_mfma_f32_16x16x32_f16(
                wreg[tap], brow[r + kh], acc[r], 0, 0, 0);
        }
      }
    }

    // ---- phase B: write staged slice to ring slot (t+2)&3 ----
    if (ts < T_) {
      _Float16* dst = in_s + (ts & 3) * SLICE_HF;
#pragma unroll
      for (int k = 0; k < 16; ++k)
        dst[wbase + (k >> 1) * RST + (k & 1) * 16] = (_Float16)sv[k];
      dst[ew0] = (_Float16)ev0;
      dst[ew1] = (_Float16)ev1;
    } else if (ts == T_) {
      uint32_t* dz = (uint32_t*)(in_s + (ts & 3) * SLICE_HF);
      for (int e = tid; e < SLICE_HF / 2; e += 256) dz[e] = 0u;
    }

    // ---- gating + recurrence (packed into regs) ----
    unsigned int pk[6];
#pragma unroll
    for (int r = 0; r < 6; ++r) {
      float z0 = 1.f - 2.f / (1.f + __expf(2.f * acc[r][0]));
      float f0 = 1.f / (1.f + __expf(-acc[r][1]));
      h[r][0] = f0 * (h[r][0] - z0) + z0;
      float z1 = 1.f - 2.f / (1.f + __expf(2.f * acc[r][2]));
      float f1 = 1.f / (1.f + __expf(-acc[r][3]));
      h[r][1] = f1 * (h[r][1] - z1) + z1;
      pk[r] = packhh(h[r][0], h[r][1]);
    }
    __syncthreads();   // stage writes visible; ring slot safety

    // ---- h-stores AFTER the barrier (drain covered by next barrier) ----
#pragma unroll
    for (int r = 0; r < 6; ++r)
      gout[obase + r * W_] = pk[r];
    obase += SP_;
  }
}

// ---------------------------------------------------------------------------
// Kernel 2: per-pixel channel attention via 32x32x16 MFMA.
// == R17's PX=16 / 512-thr version (best measured ~65us; R18's PX=8
// regressed to ~80 due to halved coalescing runs). Reads packed f16x2 h
// from u32-planes b*32+pr at own (y,x) tile; writes final f32 to planes
// b*32+c at the same tile -> no cross-block aliasing.
// ---------------------------------------------------------------------------
#define APIT 40
#define PSTR 1288

__global__ __launch_bounds__(512) void attn_mfma(
    unsigned int* __restrict__ g, const float* __restrict__ gamma) {
  __shared__ _Float16 qh_s[16 * PSTR];      // 41216 B
  __shared__ _Float16 qt_s[16 * PSTR];      // 41216 B
  __shared__ _Float16 at_s[8 * 32 * APIT];  // 20480 B

  const int tid = threadIdx.x;
  const int x0 = blockIdx.x * 16;
  const int y = blockIdx.y;
  const int b = blockIdx.z;
  const int lane = tid & 63;
  const int wv = tid >> 6;       // 0..7
  const float gm = gamma[0];

  // stage packed h: 16 px x 16 pairs x 31 t u32 reads (64B runs), unpack
  for (int e = tid; e < 16 * 16 * 31; e += 512) {
    int xi = e & 15;
    int q = e >> 4;
    int t = q % 31;
    int pr = q / 31;
    unsigned int gw = g[((size_t)(b * 32 + pr) * T_ + t) * SP_ + y * W_ + x0 + xi];
    _Float16 h0 = __builtin_bit_cast(_Float16, (unsigned short)(gw & 0xffff));
    _Float16 h1 = __builtin_bit_cast(_Float16, (unsigned short)(gw >> 16));
    int c0 = 2 * pr;
    qh_s[xi * PSTR + c0 * APIT + t] = h0;
    qh_s[xi * PSTR + (c0 + 1) * APIT + t] = h1;
    qt_s[xi * PSTR + t * APIT + c0] = h0;
    qt_s[xi * PSTR + t * APIT + c0 + 1] = h1;
  }
  qh_s[(tid & 15) * PSTR + (tid >> 4) * APIT + 31] = (_Float16)0.f;
  __syncthreads();

  const int cd = lane & 31;
  const int hi = lane >> 5;

#pragma unroll
  for (int pp = 0; pp < 2; ++pp) {
    const int px = wv * 2 + pp;
    const _Float16* qs = qh_s + px * PSTR;
    const _Float16* qt = qt_s + px * PSTR;
    _Float16* as = at_s + wv * (32 * APIT);

    // QK^T: S[c][d] = sum_t qh[c][t] qh[d][t]
    half8 q0 = *(const half8*)(qs + cd * APIT + hi * 8);
    half8 q1 = *(const half8*)(qs + cd * APIT + hi * 8 + 16);
    f32x16 S = {};
    S = __builtin_amdgcn_mfma_f32_32x32x16_f16(q0, q0, S, 0, 0, 0);
    S = __builtin_amdgcn_mfma_f32_32x32x16_f16(q1, q1, S, 0, 0, 0);

    // softmax over c (rows in regs + lane^32), then * 1/sqrt(32)
    float mx = S[0];
#pragma unroll
    for (int r = 1; r < 16; ++r) mx = fmaxf(mx, S[r]);
    mx = fmaxf(mx, __shfl_xor(mx, 32));
    float sm = 0.f;
    float ev[16];
#pragma unroll
    for (int r = 0; r < 16; ++r) { ev[r] = __expf(S[r] - mx); sm += ev[r]; }
    sm += __shfl_xor(sm, 32);
    const float sc = 0.17677669529663688f / sm;

#pragma unroll
    for (int r = 0; r < 16; ++r) {
      int c = (r & 3) + 8 * (r >> 2) + 4 * hi;
      as[c * APIT + cd] = (_Float16)(ev[r] * sc);
    }

    // PV: P[c][t] = sum_d attn[c][d] qh[d][t]
    half8 a0 = *(const half8*)(as + cd * APIT + hi * 8);
    half8 a1 = *(const half8*)(as + cd * APIT + hi * 8 + 16);
    half8 b0 = *(const half8*)(qt + cd * APIT + hi * 8);
    half8 b1 = *(const half8*)(qt + cd * APIT + hi * 8 + 16);
    f32x16 P = {};
    P = __builtin_amdgcn_mfma_f32_32x32x16_f16(a0, b0, P, 0, 0, 0);
    P = __builtin_amdgcn_mfma_f32_32x32x16_f16(a1, b1, P, 0, 0, 0);

    // result (lane holds t = cd, c in regs) -> qt[t*APIT + c]
#pragma unroll
    for (int r = 0; r < 16; ++r) {
      int c = (r & 3) + 8 * (r >> 2) + 4 * hi;
      qt_s[px * PSTR + cd * APIT + c] = (_Float16)P[r];
    }
  }
  __syncthreads();

  // store: out = gamma * ah + h (64B float4 runs)
  float* gf = (float*)g;
  for (int e = tid; e < 4 * 992; e += 512) {
    int xi4 = e & 3;
    int q = e >> 2;
    int t = q % 31;
    int c = q / 31;
    float4 rv;
#pragma unroll
    for (int j = 0; j < 4; ++j) {
      int xi = xi4 * 4 + j;
      float ah = (float)qt_s[xi * PSTR + t * APIT + c];
      float hv = (float)qh_s[xi * PSTR + c * APIT + t];
      (&rv.x)[j] = gm * ah + hv;
    }
    *(float4*)&gf[((size_t)(b * HID_ + c) * T_ + t) * SP_ + y * W_ + x0 +
                  xi4 * 4] = rv;
  }
}

// ---------------------------------------------------------------------------
extern "C" void kernel_launch(void* const* d_in, const int* in_sizes, int n_in,
                              void* d_out, int out_size, void* d_ws,
                              size_t ws_size, hipStream_t stream) {
  const float* in    = (const float*)d_in[0];  // [4,32,31,96,96]
  const float* w     = (const float*)d_in[1];  // [64,32,3,3,3]
  const float* bias  = (const float*)d_in[2];  // [64]
  const float* gamma = (const float*)d_in[3];  // [1]
  _Float16* wr = (_Float16*)d_ws;              // 110 KB fp16 fragments

  prep_w_kernel<<<216, 256, 0, stream>>>(w, wr);
  conv_rec_mfma<<<dim3(96, 4), 256, 0, stream>>>(
      in, wr, bias, (unsigned int*)d_out);
  attn_mfma<<<dim3(6, 96, 4), 512, 0, stream>>>(
      (unsigned int*)d_out, gamma);
}

// Round 20
// 231.726 us; speedup vs baseline: 2.7429x; 1.1663x over previous
//
#include <hip/hip_runtime.h>
#include <math.h>

#define B_ 4
#define CIN_ 32
#define HID_ 32
#define T_ 31
#define H_ 96
#define W_ 96
#define SP_ (H_*W_)
#define TSP (T_ * SP_)

typedef _Float16 half8 __attribute__((ext_vector_type(8)));
typedef float f32x4 __attribute__((ext_vector_type(4)));
typedef float f32x16 __attribute__((ext_vector_type(16)));

static __device__ inline unsigned int packhh(float a, float b) {
  unsigned short ua = __builtin_bit_cast(unsigned short, (_Float16)a);
  unsigned short ub = __builtin_bit_cast(unsigned short, (_Float16)b);
  return (unsigned int)ua | ((unsigned int)ub << 16);
}

// ---------------------------------------------------------------------------
// Kernel 0: weights fp32 -> fp16 gate-interleaved MFMA A-fragments.
// wr[((ocg*27 + tap)*64 + lane)*8 + i]
//   m = lane&15: gate = m&1, ch = ocg*8 + (m>>1); oc = gate*32 + ch
//   cin = (lane>>4)*8 + i
// ---------------------------------------------------------------------------
__global__ __launch_bounds__(256) void prep_w_kernel(
    const float* __restrict__ w, _Float16* __restrict__ wr) {
  int idx = blockIdx.x * 256 + threadIdx.x;
  if (idx >= 55296) return;
  int i = idx & 7;
  int lane = (idx >> 3) & 63;
  int rest = idx >> 9;             // ocg*27 + tap
  int tap = rest % 27;
  int ocg = rest / 27;
  int m = lane & 15;
  int cin = (lane >> 4) * 8 + i;
  int oc = (m & 1) * 32 + ocg * 8 + (m >> 1);
  wr[idx] = (_Float16)(w[(oc * CIN_ + cin) * 27 + tap]);
}

// ---------------------------------------------------------------------------
// Kernel 1: fused Conv3d (fp16 MFMA) + gating + SERIAL time recurrence.
// == R18/R19 verbatim (best measured: 196-198us). FINAL.
// ---------------------------------------------------------------------------
#define PITCH 40
#define SROWS 8
#define SCOLS 18
#define RST (SCOLS * PITCH)                // 720 halfs per LDS row
#define SLICE_HF (SROWS * RST)             // 5760 f16 = 11520 B

__global__ __launch_bounds__(256, 2) void conv_rec_mfma(
    const float* __restrict__ in, const _Float16* __restrict__ wr,
    const float* __restrict__ bias, unsigned int* __restrict__ gout) {
  __shared__ _Float16 in_s[4 * SLICE_HF];   // 46080 B

  const int tid = threadIdx.x;
  const int tile = blockIdx.x;   // 0..95
  const int b = blockIdx.y;      // 0..3
  const int x0 = (tile % 6) * 16;
  const int y0 = (tile / 6) * 6;
  const int lane = tid & 63;
  const int ocg = tid >> 6;      // 0..3
  const int px = lane & 15;
  const int kq = lane >> 4;      // 0..3

  half8 wreg[27];
  {
    const _Float16* wp = wr + (size_t)ocg * 27 * 512 + lane * 8;
#pragma unroll
    for (int tap = 0; tap < 27; ++tap)
      wreg[tap] = *(const half8*)(wp + tap * 512);
  }

  const int c0 = ocg * 8 + 2 * kq;
  f32x4 bias4;
  bias4[0] = bias[c0];
  bias4[1] = bias[32 + c0];
  bias4[2] = bias[c0 + 1];
  bias4[3] = bias[32 + c0 + 1];

  const int s_xi = tid & 15;
  const int s_q  = tid >> 4;       // 0..15
  const int ibase = s_q * TSP + (y0 - 1) * W_ + x0 + s_xi;
  const int wbase = (s_xi + 1) * PITCH + s_q;
  const int e_cin = tid & 31;
  const int e_yy  = tid >> 5;
  const int e_gy  = y0 - 1 + e_yy;
  const bool e_ok = ((unsigned)e_gy < (unsigned)H_);
  const int eoff  = e_cin * TSP + e_gy * W_;
  const int ew0   = e_yy * RST + 0 * PITCH + e_cin;
  const int ew1   = e_yy * RST + 17 * PITCH + e_cin;
  const bool has_l = (x0 > 0), has_r = (x0 + 16 < W_);

  int cs[3];
#pragma unroll
  for (int kw = 0; kw < 3; ++kw) cs[kw] = (px + kw) * PITCH + kq * 8;

  const float* inb = in + (size_t)(b * CIN_) * TSP;

  auto stage_full = [&](int ts) {   // prologue only
    _Float16* dst = in_s + (ts & 3) * SLICE_HF;
    const int tso = ts * SP_;
#pragma unroll
    for (int k = 0; k < 16; ++k) {
      const int gy = y0 - 1 + (k >> 1);
      float v = 0.f;
      if ((unsigned)gy < (unsigned)H_)
        v = inb[ibase + (k & 1) * 16 * TSP + (k >> 1) * W_ + tso];
      dst[wbase + (k >> 1) * RST + (k & 1) * 16] = (_Float16)v;
    }
    float v0 = 0.f, v1 = 0.f;
    if (e_ok) {
      if (has_l) v0 = inb[eoff + tso + x0 - 1];
      if (has_r) v1 = inb[eoff + tso + x0 + 16];
    }
    dst[ew0] = (_Float16)v0;
    dst[ew1] = (_Float16)v1;
  };

  {
    uint32_t* dz = (uint32_t*)(in_s + 3 * SLICE_HF);
    for (int e = tid; e < SLICE_HF / 2; e += 256) dz[e] = 0u;
  }
  stage_full(0);
  stage_full(1);
  __syncthreads();

  float h[6][2];
#pragma unroll
  for (int r = 0; r < 6; ++r) { h[r][0] = 0.f; h[r][1] = 0.f; }

  const int pr = ocg * 4 + kq;   // packed pair plane 0..15
  size_t obase = ((size_t)(b * 32 + pr) * T_) * SP_ + y0 * W_ + x0 + px;

  for (int t = 0; t < T_; ++t) {
    const int ts = t + 2;

    float sv[16], ev0 = 0.f, ev1 = 0.f;
    if (ts < T_) {
      const int tso = ts * SP_;
#pragma unroll
      for (int k = 0; k < 16; ++k) {
        const int gy = y0 - 1 + (k >> 1);
        sv[k] = 0.f;
        if ((unsigned)gy < (unsigned)H_)
          sv[k] = inb[ibase + (k & 1) * 16 * TSP + (k >> 1) * W_ + tso];
      }
      if (e_ok) {
        if (has_l) ev0 = inb[eoff + tso + x0 - 1];
        if (has_r) ev1 = inb[eoff + tso + x0 + 16];
      }
    }

    f32x4 acc[6];
#pragma unroll
    for (int r = 0; r < 6; ++r) acc[r] = bias4;

#pragma unroll
    for (int kd = 0; kd < 3; ++kd) {
      const _Float16* sb2 = in_s + ((t + 3 + kd) & 3) * SLICE_HF;  // slice t-1+kd
#pragma unroll
      for (int kw = 0; kw < 3; ++kw) {
        half8 brow[8];
#pragma unroll
        for (int rr = 0; rr < 8; ++rr)
          brow[rr] = *(const half8*)(sb2 + rr * RST + cs[kw]);
#pragma unroll
        for (int kh = 0; kh < 3; ++kh) {
          const int tap = kd * 9 + kh * 3 + kw;
#pragma unroll
          for (int r = 0; r < 6; ++r)
            acc[r] = __builtin_amdgcn_mfma_f32_16x16x32_f16(
                wreg[tap], brow[r + kh], acc[r], 0, 0, 0);
        }
      }
    }

    if (ts < T_) {
      _Float16* dst = in_s + (ts & 3) * SLICE_HF;
#pragma unroll
      for (int k = 0; k < 16; ++k)
        dst[wbase + (k >> 1) * RST + (k & 1) * 16] = (_Float16)sv[k];
      dst[ew0] = (_Float16)ev0;
      dst[ew1] = (_Float16)ev1;
    } else if (ts == T_) {
      uint32_t* dz = (uint32_t*)(in_s + (ts & 3) * SLICE_HF);
      for (int e = tid; e < SLICE_HF / 2; e += 256) dz[e] = 0u;
    }

    unsigned int pk[6];
#pragma unroll
    for (int r = 0; r < 6; ++r) {
      float z0 = 1.f - 2.f / (1.f + __expf(2.f * acc[r][0]));
      float f0 = 1.f / (1.f + __expf(-acc[r][1]));
      h[r][0] = f0 * (h[r][0] - z0) + z0;
      float z1 = 1.f - 2.f / (1.f + __expf(2.f * acc[r][2]));
      float f1 = 1.f / (1.f + __expf(-acc[r][3]));
      h[r][1] = f1 * (h[r][1] - z1) + z1;
      pk[r] = packhh(h[r][0], h[r][1]);
    }
    __syncthreads();

#pragma unroll
    for (int r = 0; r < 6; ++r)
      gout[obase + r * W_] = pk[r];
    obase += SP_;
  }
}

// ---------------------------------------------------------------------------
// Kernel 2: PERSISTENT per-pixel channel attention via 32x32x16 MFMA.
// Grid = 256 blocks x 9 tiles each (2304 = 256*9 exact; ti = bid + 256k for
// cross-block L2 locality). Per tile: unpack regs->LDS, issue NEXT tile's
// 16 u32 loads into the same regs (WAR after unpack), barrier, compute,
// barrier, store, barrier. Next tile's HBM latency hides under current
// tile's compute+store. qt staging = single aligned u32 write (c0,c0+1
// adjacent). Same PX=16 geometry / LDS as R19 (proven ~65us single-shot).
// ---------------------------------------------------------------------------
#define APIT 40
#define PSTR 1288
#define NTILES 2304
#define TPB 9

__global__ __launch_bounds__(512) void attn_mfma(
    unsigned int* __restrict__ g, const float* __restrict__ gamma) {
  __shared__ _Float16 qh_s[16 * PSTR];      // 41216 B
  __shared__ _Float16 qt_s[16 * PSTR];      // 41216 B
  __shared__ _Float16 at_s[8 * 32 * APIT];  // 20480 B

  const int tid = threadIdx.x;
  const int bid = blockIdx.x;    // 0..255
  const int lane = tid & 63;
  const int wv = tid >> 6;       // 0..7
  const float gm = gamma[0];
  const int xi = tid & 15;
  const int q0 = tid >> 4;       // 0..31
  const int cd = lane & 31;
  const int hi = lane >> 5;

  unsigned int sv[16];

  // prologue: load tile bid
  {
    int ti = bid;
    int xt = ti % 6; int rem = ti / 6; int y = rem % 96; int b = rem / 96;
    const unsigned int* gb =
        g + (size_t)(b * 32) * TSP + y * W_ + xt * 16 + xi;
#pragma unroll
    for (int k2 = 0; k2 < 16; ++k2) {
      int q = q0 + 32 * k2;
      int t = q % 31;
      int pr = q / 31;
      if (q < 496) sv[k2] = gb[(size_t)(pr * T_ + t) * SP_];
    }
  }

  int ti = bid;
  for (int k = 0; k < TPB; ++k) {
    // current tile coords
    const int xt = ti % 6;
    const int rem = ti / 6;
    const int y = rem % 96;
    const int b = rem / 96;
    const int x0 = xt * 16;

    // ---- unpack sv -> qh/qt (reads sv) ----
#pragma unroll
    for (int k2 = 0; k2 < 16; ++k2) {
      int q = q0 + 32 * k2;
      int t = q % 31;
      int pr = q / 31;
      if (q < 496) {
        unsigned int gw = sv[k2];
        _Float16 h0 = __builtin_bit_cast(_Float16, (unsigned short)(gw & 0xffff));
        _Float16 h1 = __builtin_bit_cast(_Float16, (unsigned short)(gw >> 16));
        int c0 = 2 * pr;
        qh_s[xi * PSTR + c0 * APIT + t] = h0;
        qh_s[xi * PSTR + (c0 + 1) * APIT + t] = h1;
        *(unsigned int*)&qt_s[xi * PSTR + t * APIT + c0] = gw;  // aligned
      }
    }
    qh_s[xi * PSTR + q0 * APIT + 31] = (_Float16)0.f;  // t-pad (16px x 32c)

    // ---- issue loads for next tile into sv (WAR after unpack) ----
    if (k + 1 < TPB) {
      int tn = ti + 256;
      int xt2 = tn % 6; int rem2 = tn / 6; int y2 = rem2 % 96; int b2 = rem2 / 96;
      const unsigned int* gb =
          g + (size_t)(b2 * 32) * TSP + y2 * W_ + xt2 * 16 + xi;
#pragma unroll
      for (int k2 = 0; k2 < 16; ++k2) {
        int q = q0 + 32 * k2;
        int t = q % 31;
        int pr = q / 31;
        if (q < 496) sv[k2] = gb[(size_t)(pr * T_ + t) * SP_];
      }
    }
    __syncthreads();

    // ---- compute: QK^T -> softmax -> PV (2 px per wave) ----
#pragma unroll
    for (int pp = 0; pp < 2; ++pp) {
      const int px = wv * 2 + pp;
      const _Float16* qs = qh_s + px * PSTR;
      const _Float16* qt = qt_s + px * PSTR;
      _Float16* as = at_s + wv * (32 * APIT);

      half8 a0q = *(const half8*)(qs + cd * APIT + hi * 8);
      half8 a1q = *(const half8*)(qs + cd * APIT + hi * 8 + 16);
      f32x16 S = {};
      S = __builtin_amdgcn_mfma_f32_32x32x16_f16(a0q, a0q, S, 0, 0, 0);
      S = __builtin_amdgcn_mfma_f32_32x32x16_f16(a1q, a1q, S, 0, 0, 0);

      float mx = S[0];
#pragma unroll
      for (int r = 1; r < 16; ++r) mx = fmaxf(mx, S[r]);
      mx = fmaxf(mx, __shfl_xor(mx, 32));
      float sm = 0.f;
      float ev[16];
#pragma unroll
      for (int r = 0; r < 16; ++r) { ev[r] = __expf(S[r] - mx); sm += ev[r]; }
      sm += __shfl_xor(sm, 32);
      const float sc = 0.17677669529663688f / sm;

#pragma unroll
      for (int r = 0; r < 16; ++r) {
        int c = (r & 3) + 8 * (r >> 2) + 4 * hi;
        as[c * APIT + cd] = (_Float16)(ev[r] * sc);
      }

      half8 a0 = *(const half8*)(as + cd * APIT + hi * 8);
      half8 a1 = *(const half8*)(as + cd * APIT + hi * 8 + 16);
      half8 b0 = *(const half8*)(qt + cd * APIT + hi * 8);
      half8 b1 = *(const half8*)(qt + cd * APIT + hi * 8 + 16);
      f32x16 P = {};
      P = __builtin_amdgcn_mfma_f32_32x32x16_f16(a0, b0, P, 0, 0, 0);
      P = __builtin_amdgcn_mfma_f32_32x32x16_f16(a1, b1, P, 0, 0, 0);

#pragma unroll
      for (int r = 0; r < 16; ++r) {
        int c = (r & 3) + 8 * (r >> 2) + 4 * hi;
        qt_s[px * PSTR + cd * APIT + c] = (_Float16)P[r];
      }
    }
    __syncthreads();

    // ---- store: out = gamma * ah + h (64B float4 runs) ----
    float* gf = (float*)g;
    for (int e = tid; e < 4 * 992; e += 512) {
      int xi4 = e & 3;
      int q = e >> 2;
      int t = q % 31;
      int c = q / 31;
      float4 rv;
#pragma unroll
      for (int j = 0; j < 4; ++j) {
        int x2 = xi4 * 4 + j;
        float ah = (float)qt_s[x2 * PSTR + t * APIT + c];
        float hv = (float)qh_s[x2 * PSTR + c * APIT + t];
        (&rv.x)[j] = gm * ah + hv;
      }
      *(float4*)&gf[((size_t)(b * HID_ + c) * T_ + t) * SP_ + y * W_ + x0 +
                    xi4 * 4] = rv;
    }
    ti += 256;
    __syncthreads();   // LDS protected before next unpack
  }
}

// ---------------------------------------------------------------------------
extern "C" void kernel_launch(void* const* d_in, const int* in_sizes, int n_in,
                              void* d_out, int out_size, void* d_ws,
                              size_t ws_size, hipStream_t stream) {
  const float* in    = (const float*)d_in[0];  // [4,32,31,96,96]
  const float* w     = (const float*)d_in[1];  // [64,32,3,3,3]
  const float* bias  = (const float*)d_in[2];  // [64]
  const float* gamma = (const float*)d_in[3];  // [1]
  _Float16* wr = (_Float16*)d_ws;              // 110 KB fp16 fragments

  prep_w_kernel<<<216, 256, 0, stream>>>(w, wr);
  conv_rec_mfma<<<dim3(96, 4), 256, 0, stream>>>(
      in, wr, bias, (unsigned int*)d_out);
  attn_mfma<<<dim3(256), 512, 0, stream>>>(
      (unsigned int*)d_out, gamma);
}